// Round 1
// baseline (276.498 us; speedup 1.0000x reference)
//
#include <hip/hip_runtime.h>

#define N_NODES 50000
#define D_FEAT 64
#define N_NNZ 800000
#define N_ENT 65536   // 2 * 32768 edge endpoints

typedef unsigned int uint32;
typedef unsigned short ushort16;

// ---- bf16 helpers ---------------------------------------------------------
__device__ __forceinline__ uint32 rne1(float a) {
    uint32 u = __float_as_uint(a);
    return (u + 0x7FFFu + ((u >> 16) & 1u)) >> 16;
}
__device__ __forceinline__ uint32 rne2(float a, float b) {   // pack [a:lo, b:hi]
    return rne1(a) | (rne1(b) << 16);
}
__device__ __forceinline__ float bf_lo(uint32 u) { return __uint_as_float(u << 16); }
__device__ __forceinline__ float bf_hi(uint32 u) { return __uint_as_float(u & 0xFFFF0000u); }
__device__ __forceinline__ void unpack8(const uint4 v, float* f) {
    f[0] = bf_lo(v.x); f[1] = bf_hi(v.x);
    f[2] = bf_lo(v.y); f[3] = bf_hi(v.y);
    f[4] = bf_lo(v.z); f[5] = bf_hi(v.z);
    f[6] = bf_lo(v.w); f[7] = bf_hi(v.w);
}
__device__ __forceinline__ float bf1(ushort16 u) { return __uint_as_float(((uint32)u) << 16); }

// ---------------------------------------------------------------------------
// 1a) CSR row pointers (binary search over sorted adj_row) + per-node scalars
//     scal[n] = {1/deg, rsqrt(deg), sqrt(deg), 0}
// ---------------------------------------------------------------------------
__global__ void build_rowptr_scal(const int* __restrict__ adj_row,
                                  const float* __restrict__ deg,
                                  int* __restrict__ row_ptr,
                                  float4* __restrict__ scal,
                                  int nnz, int n) {
    int r = blockIdx.x * blockDim.x + threadIdx.x;
    if (r > n) return;
    int lo = 0, hi = nnz;           // first idx with adj_row[idx] >= r
    while (lo < hi) {
        int mid = (lo + hi) >> 1;
        if (adj_row[mid] < r) lo = mid + 1; else hi = mid;
    }
    row_ptr[r] = lo;
    if (r < n) {
        float d  = deg[r];
        float sq = sqrtf(d);
        scal[r] = make_float4(1.0f / d, 1.0f / sq, sq, 0.0f);
    }
}

// 1b) x (fp32) -> xh (bf16 pairs). 50000*64/2 = 1.6M uint32.
__global__ __launch_bounds__(256) void pack_x(const float2* __restrict__ x2,
                                              uint32* __restrict__ xh, int npair) {
    int i = blockIdx.x * blockDim.x + threadIdx.x;
    if (i >= npair) return;
    float2 v = x2[i];
    xh[i] = rne2(v.x, v.y);
}

// ---------------------------------------------------------------------------
// 2) y1 = degrev * spmm(x3). x3 groups are x scaled per-SOURCE-node, so we
//    gather only xh[c] (128B bf16) + scal[c].
//    NEW layout: one WAVE per row; 8 octets each take every-8th neighbor
//    (2-way unrolled -> 16 neighbors in flight / wave). Kills the serial
//    per-octet walk (mean 8, max ~13 dependent iterations) and the
//    inter-octet Poisson imbalance. Cross-octet shfl_xor reduce at end.
// ---------------------------------------------------------------------------
__global__ __launch_bounds__(256) void spmm1_kernel(
    const uint4* __restrict__ xh, const float4* __restrict__ scal,
    const int* __restrict__ adj_col, const int* __restrict__ row_ptr,
    uint4* __restrict__ y1h, int n) {
    int t = threadIdx.x & 63;
    int f = t & 7;                                  // feature block
    int o = t >> 3;                                 // octet id (0..7)
    int r = blockIdx.x * 4 + (threadIdx.x >> 6);    // one wave per row
    if (r >= n) return;

    int s = row_ptr[r], e = row_ptr[r + 1];
    float a0[8], a1[8], a2[8];
#pragma unroll
    for (int j = 0; j < 8; ++j) { a0[j] = 0.f; a1[j] = 0.f; a2[j] = 0.f; }

    for (int i = s + o; i < e; i += 16) {           // octet o: residues o, o+8
        int  c0 = adj_col[i];
        int  i1 = i + 8;
        bool p1 = i1 < e;
        int  c1 = adj_col[p1 ? i1 : i];
        uint4  xv0 = xh[(size_t)c0 * 8 + f];
        float4 sc0 = scal[c0];
        uint4  xv1 = xh[(size_t)c1 * 8 + f];
        float4 sc1 = scal[c1];
        float xf0[8], xf1[8];
        unpack8(xv0, xf0); unpack8(xv1, xf1);
#pragma unroll
        for (int j = 0; j < 8; ++j) {
            a0[j] += xf0[j];
            a1[j] += xf0[j] * sc0.y;
            a2[j] += xf0[j] * sc0.z;
        }
        if (p1) {
#pragma unroll
            for (int j = 0; j < 8; ++j) {
                a0[j] += xf1[j];
                a1[j] += xf1[j] * sc1.y;
                a2[j] += xf1[j] * sc1.z;
            }
        }
    }

    // cross-octet reduction: sum lanes differing in bits 3..5
#pragma unroll
    for (int j = 0; j < 8; ++j) {
        a0[j] += __shfl_xor(a0[j], 8);
        a1[j] += __shfl_xor(a1[j], 8);
        a2[j] += __shfl_xor(a2[j], 8);
    }
#pragma unroll
    for (int j = 0; j < 8; ++j) {
        a0[j] += __shfl_xor(a0[j], 16);
        a1[j] += __shfl_xor(a1[j], 16);
        a2[j] += __shfl_xor(a2[j], 16);
    }
#pragma unroll
    for (int j = 0; j < 8; ++j) {
        a0[j] += __shfl_xor(a0[j], 32);
        a1[j] += __shfl_xor(a1[j], 32);
        a2[j] += __shfl_xor(a2[j], 32);
    }

    if (t < 8) {                                    // f == t
        float dr = scal[r].x;
        uint4* yr = y1h + (size_t)r * 24 + t;
        yr[0]  = make_uint4(rne2(a0[0]*dr, a0[1]*dr), rne2(a0[2]*dr, a0[3]*dr),
                            rne2(a0[4]*dr, a0[5]*dr), rne2(a0[6]*dr, a0[7]*dr));
        yr[8]  = make_uint4(rne2(a1[0]*dr, a1[1]*dr), rne2(a1[2]*dr, a1[3]*dr),
                            rne2(a1[4]*dr, a1[5]*dr), rne2(a1[6]*dr, a1[7]*dr));
        yr[16] = make_uint4(rne2(a2[0]*dr, a2[1]*dr), rne2(a2[2]*dr, a2[3]*dr),
                            rne2(a2[4]*dr, a2[5]*dr), rne2(a2[6]*dr, a2[7]*dr));
    }
}

// ---------------------------------------------------------------------------
// 3) y2 = degrev * spmm(y1) - x3. Gathers bf16 y1 rows (384B/neighbor),
//    same wave-per-row neighbor-parallel structure; 3 uint4 loads/neighbor
//    -> up to 48 outstanding 16B gathers per wave.
// ---------------------------------------------------------------------------
__global__ __launch_bounds__(256) void spmm2_kernel(
    const float4* __restrict__ x4, const float4* __restrict__ scal,
    const int* __restrict__ adj_col, const int* __restrict__ row_ptr,
    const uint4* __restrict__ y1h, uint4* __restrict__ y2h, int n) {
    int t = threadIdx.x & 63;
    int f = t & 7;
    int o = t >> 3;
    int r = blockIdx.x * 4 + (threadIdx.x >> 6);
    if (r >= n) return;

    int s = row_ptr[r], e = row_ptr[r + 1];
    float a0[8], a1[8], a2[8];
#pragma unroll
    for (int j = 0; j < 8; ++j) { a0[j] = 0.f; a1[j] = 0.f; a2[j] = 0.f; }

    for (int i = s + o; i < e; i += 16) {
        int  c0 = adj_col[i];
        int  i1 = i + 8;
        bool p1 = i1 < e;
        int  c1 = adj_col[p1 ? i1 : i];
        const uint4* yc0 = y1h + (size_t)c0 * 24 + f;
        const uint4* yc1 = y1h + (size_t)c1 * 24 + f;
        uint4 b0 = yc0[0], b1 = yc0[8], b2 = yc0[16];
        uint4 d0 = yc1[0], d1 = yc1[8], d2 = yc1[16];
        float f0[8], f1[8], f2[8], g0[8], g1[8], g2[8];
        unpack8(b0, f0); unpack8(b1, f1); unpack8(b2, f2);
        unpack8(d0, g0); unpack8(d1, g1); unpack8(d2, g2);
#pragma unroll
        for (int j = 0; j < 8; ++j) {
            a0[j] += f0[j];
            a1[j] += f1[j];
            a2[j] += f2[j];
        }
        if (p1) {
#pragma unroll
            for (int j = 0; j < 8; ++j) {
                a0[j] += g0[j];
                a1[j] += g1[j];
                a2[j] += g2[j];
            }
        }
    }

#pragma unroll
    for (int j = 0; j < 8; ++j) {
        a0[j] += __shfl_xor(a0[j], 8);
        a1[j] += __shfl_xor(a1[j], 8);
        a2[j] += __shfl_xor(a2[j], 8);
    }
#pragma unroll
    for (int j = 0; j < 8; ++j) {
        a0[j] += __shfl_xor(a0[j], 16);
        a1[j] += __shfl_xor(a1[j], 16);
        a2[j] += __shfl_xor(a2[j], 16);
    }
#pragma unroll
    for (int j = 0; j < 8; ++j) {
        a0[j] += __shfl_xor(a0[j], 32);
        a1[j] += __shfl_xor(a1[j], 32);
        a2[j] += __shfl_xor(a2[j], 32);
    }

    if (t < 8) {
        float4 sc = scal[r];                       // {1/d, rsqrt, sqrt, 0}
        float4 xa = x4[(size_t)r * 16 + t * 2];
        float4 xb = x4[(size_t)r * 16 + t * 2 + 1];
        float xr[8] = {xa.x, xa.y, xa.z, xa.w, xb.x, xb.y, xb.z, xb.w};
        float v0[8], v1[8], v2[8];
#pragma unroll
        for (int j = 0; j < 8; ++j) {
            v0[j] = sc.x * a0[j] - xr[j];
            v1[j] = sc.x * a1[j] - xr[j] * sc.y;
            v2[j] = sc.x * a2[j] - xr[j] * sc.z;
        }
        uint4* yr = y2h + (size_t)r * 24 + t;
        yr[0]  = make_uint4(rne2(v0[0], v0[1]), rne2(v0[2], v0[3]),
                            rne2(v0[4], v0[5]), rne2(v0[6], v0[7]));
        yr[8]  = make_uint4(rne2(v1[0], v1[1]), rne2(v1[2], v1[3]),
                            rne2(v1[4], v1[5]), rne2(v1[6], v1[7]));
        yr[16] = make_uint4(rne2(v2[0], v2[1]), rne2(v2[2], v2[3]),
                            rne2(v2[4], v2[5]), rne2(v2[6], v2[7]));
    }
}

// ---------------------------------------------------------------------------
// 4) Output gather + [64,9] transpose through LDS; float4 store path.
//    out[ent, d, g]: g 0..2 = x*{1,rsqrt,sqrt}, g 3..5 = y1, g 6..8 = y2.
// ---------------------------------------------------------------------------
__global__ __launch_bounds__(256) void gather_kernel(
    const float* __restrict__ x, const float4* __restrict__ scal,
    const int* __restrict__ edge, const ushort16* __restrict__ y1h,
    const ushort16* __restrict__ y2h, float* __restrict__ out) {
    __shared__ __align__(16) float lds[4][576];
    int wave = threadIdx.x >> 6;
    int t    = threadIdx.x & 63;
    int ent  = blockIdx.x * 4 + wave;

    int n = edge[ent];
    float4 sc = scal[n];                       // {1/d, rsqrt, sqrt, 0}
    float xv = x[n * D_FEAT + t];
    const ushort16* y1n = y1h + (size_t)n * 192;
    const ushort16* y2n = y2h + (size_t)n * 192;

    float h[9];
    h[0] = xv;              h[1] = xv * sc.y;        h[2] = xv * sc.z;
    h[3] = bf1(y1n[t]);     h[4] = bf1(y1n[64 + t]); h[5] = bf1(y1n[128 + t]);
    h[6] = bf1(y2n[t]);     h[7] = bf1(y2n[64 + t]); h[8] = bf1(y2n[128 + t]);

#pragma unroll
    for (int g = 0; g < 9; ++g) lds[wave][t * 9 + g] = h[g];  // 2-way alias: free
    __syncthreads();

    const float4* l4 = (const float4*)lds[wave];
    float4* o4 = (float4*)(out + (size_t)ent * 576);   // 144 float4 per entry
    o4[t]      = l4[t];
    o4[t + 64] = l4[t + 64];
    if (t < 16) o4[t + 128] = l4[t + 128];
}

// ---------------------------------------------------------------------------
extern "C" void kernel_launch(void* const* d_in, const int* in_sizes, int n_in,
                              void* d_out, int out_size, void* d_ws, size_t ws_size,
                              hipStream_t stream) {
    const float* x       = (const float*)d_in[0];   // [N, 64]
    const float* deg     = (const float*)d_in[1];   // [N, 1]
    const int*   adj_row = (const int*)d_in[2];     // [nnz] sorted
    const int*   adj_col = (const int*)d_in[3];     // [nnz]
    const int*   edge    = (const int*)d_in[4];     // [2, 32768]
    float* out = (float*)d_out;

    // Workspace (rewritten fully every call):
    //   row_ptr : (N+1) int        scal : N float4
    //   xh      : N*64 bf16        y1h  : N*192 bf16    y2h : N*192 bf16
    char* ws = (char*)d_ws;
    size_t off = 0;
    int*    row_ptr = (int*)ws;            off = ((size_t)(N_NODES + 1) * 4 + 255) & ~(size_t)255;
    float4* scal    = (float4*)(ws + off); off += (size_t)N_NODES * 16;
    uint32* xh      = (uint32*)(ws + off); off += (size_t)N_NODES * 64 * 2;
    off = (off + 255) & ~(size_t)255;
    uint4*  y1h     = (uint4*)(ws + off);  off += (size_t)N_NODES * 192 * 2;
    off = (off + 255) & ~(size_t)255;
    uint4*  y2h     = (uint4*)(ws + off);

    build_rowptr_scal<<<(N_NODES + 1 + 255) / 256, 256, 0, stream>>>(
        adj_row, deg, row_ptr, scal, N_NNZ, N_NODES);
    pack_x<<<(N_NODES * 32 + 255) / 256, 256, 0, stream>>>(
        (const float2*)x, xh, N_NODES * 32);
    spmm1_kernel<<<(N_NODES + 3) / 4, 256, 0, stream>>>(
        (const uint4*)xh, scal, adj_col, row_ptr, y1h, N_NODES);
    spmm2_kernel<<<(N_NODES + 3) / 4, 256, 0, stream>>>(
        (const float4*)x, scal, adj_col, row_ptr, y1h, y2h, N_NODES);
    gather_kernel<<<N_ENT / 4, 256, 0, stream>>>(
        x, scal, edge, (const ushort16*)y1h, (const ushort16*)y2h, out);
}

// Round 2
// 255.044 us; speedup vs baseline: 1.0841x; 1.0841x over previous
//
#include <hip/hip_runtime.h>

#define N_NODES 50000
#define D_FEAT 64
#define N_NNZ 800000
#define N_ENT 65536   // 2 * 32768 edge endpoints

typedef unsigned int uint32;
typedef unsigned short ushort16;

// Plane strides for plane-major [3][N][64] bf16 tables
#define PLANE_U4 ((size_t)N_NODES * 8)    // in uint4 (16B) units
#define PLANE_US ((size_t)N_NODES * 64)   // in ushort units

// ---- bf16 helpers ---------------------------------------------------------
__device__ __forceinline__ uint32 rne1(float a) {
    uint32 u = __float_as_uint(a);
    return (u + 0x7FFFu + ((u >> 16) & 1u)) >> 16;
}
__device__ __forceinline__ uint32 rne2(float a, float b) {   // pack [a:lo, b:hi]
    return rne1(a) | (rne1(b) << 16);
}
__device__ __forceinline__ float bf_lo(uint32 u) { return __uint_as_float(u << 16); }
__device__ __forceinline__ float bf_hi(uint32 u) { return __uint_as_float(u & 0xFFFF0000u); }
__device__ __forceinline__ void unpack8(const uint4 v, float* f) {
    f[0] = bf_lo(v.x); f[1] = bf_hi(v.x);
    f[2] = bf_lo(v.y); f[3] = bf_hi(v.y);
    f[4] = bf_lo(v.z); f[5] = bf_hi(v.z);
    f[6] = bf_lo(v.w); f[7] = bf_hi(v.w);
}
__device__ __forceinline__ float bf1(ushort16 u) { return __uint_as_float(((uint32)u) << 16); }

// ---------------------------------------------------------------------------
// 1a) CSR row pointers (binary search over sorted adj_row) + per-node scalars
//     scal[n] = {1/deg, rsqrt(deg), sqrt(deg), 0}
// ---------------------------------------------------------------------------
__global__ void build_rowptr_scal(const int* __restrict__ adj_row,
                                  const float* __restrict__ deg,
                                  int* __restrict__ row_ptr,
                                  float4* __restrict__ scal,
                                  int nnz, int n) {
    int r = blockIdx.x * blockDim.x + threadIdx.x;
    if (r > n) return;
    int lo = 0, hi = nnz;           // first idx with adj_row[idx] >= r
    while (lo < hi) {
        int mid = (lo + hi) >> 1;
        if (adj_row[mid] < r) lo = mid + 1; else hi = mid;
    }
    row_ptr[r] = lo;
    if (r < n) {
        float d  = deg[r];
        float sq = sqrtf(d);
        scal[r] = make_float4(1.0f / d, 1.0f / sq, sq, 0.0f);
    }
}

// 1b) x (fp32) -> xh (bf16 pairs). 50000*64/2 = 1.6M uint32.
__global__ __launch_bounds__(256) void pack_x(const float2* __restrict__ x2,
                                              uint32* __restrict__ xh, int npair) {
    int i = blockIdx.x * blockDim.x + threadIdx.x;
    if (i >= npair) return;
    float2 v = x2[i];
    xh[i] = rne2(v.x, v.y);
}

// ---------------------------------------------------------------------------
// 2) y1 = degrev * spmm(x3). Round-0 proven structure: wave = 8 rows, each
//    8-lane octet owns one row and walks its neighbor list serially (2-way
//    MLP unroll). Gather table is xh (6.4 MB -> decent L2 residency).
//    Output now PLANE-MAJOR [3][N][64] bf16 so spmm2 can do per-group
//    passes with a 6.4 MB working set.
// ---------------------------------------------------------------------------
__global__ __launch_bounds__(256) void spmm1_kernel(
    const uint4* __restrict__ xh, const float4* __restrict__ scal,
    const int* __restrict__ adj_col, const int* __restrict__ row_ptr,
    uint4* __restrict__ y1h, int n) {
    int t    = threadIdx.x & 63;
    int f    = t & 7;                                  // feature block
    int r    = (blockIdx.x * 4 + (threadIdx.x >> 6)) * 8 + (t >> 3);
    if (r >= n) return;

    int s = row_ptr[r], e = row_ptr[r + 1];
    int cnt = e - s;
    float a0[8], a1[8], a2[8];
#pragma unroll
    for (int j = 0; j < 8; ++j) { a0[j] = 0.f; a1[j] = 0.f; a2[j] = 0.f; }

    int i = 0;
    for (; i + 2 <= cnt; i += 2) {
        int c0 = adj_col[s + i];
        int c1 = adj_col[s + i + 1];
        uint4 xv0 = xh[(size_t)c0 * 8 + f];
        uint4 xv1 = xh[(size_t)c1 * 8 + f];
        float4 sc0 = scal[c0];
        float4 sc1 = scal[c1];
        float xf0[8], xf1[8];
        unpack8(xv0, xf0); unpack8(xv1, xf1);
#pragma unroll
        for (int j = 0; j < 8; ++j) {
            a0[j] += xf0[j];
            a1[j] += xf0[j] * sc0.y;
            a2[j] += xf0[j] * sc0.z;
            a0[j] += xf1[j];
            a1[j] += xf1[j] * sc1.y;
            a2[j] += xf1[j] * sc1.z;
        }
    }
    if (i < cnt) {
        int c = adj_col[s + i];
        uint4 xv = xh[(size_t)c * 8 + f];
        float4 sc = scal[c];
        float xf[8]; unpack8(xv, xf);
#pragma unroll
        for (int j = 0; j < 8; ++j) {
            a0[j] += xf[j];
            a1[j] += xf[j] * sc.y;
            a2[j] += xf[j] * sc.z;
        }
    }

    float dr = scal[r].x;
    size_t base = (size_t)r * 8 + f;
    y1h[base]               = make_uint4(rne2(a0[0]*dr, a0[1]*dr), rne2(a0[2]*dr, a0[3]*dr),
                                         rne2(a0[4]*dr, a0[5]*dr), rne2(a0[6]*dr, a0[7]*dr));
    y1h[base + PLANE_U4]    = make_uint4(rne2(a1[0]*dr, a1[1]*dr), rne2(a1[2]*dr, a1[3]*dr),
                                         rne2(a1[4]*dr, a1[5]*dr), rne2(a1[6]*dr, a1[7]*dr));
    y1h[base + 2*PLANE_U4]  = make_uint4(rne2(a2[0]*dr, a2[1]*dr), rne2(a2[2]*dr, a2[3]*dr),
                                         rne2(a2[4]*dr, a2[5]*dr), rne2(a2[6]*dr, a2[7]*dr));
}

// ---------------------------------------------------------------------------
// 3) y2 = degrev * spmm(y1) - x3, ONE GROUP PER PASS (blockIdx.y = group).
//    x-major dispatch gives temporal phases: during phase g, every XCD's L2
//    works the same 6.4 MB y1 plane (vs 19.2 MB mixed before) -> L2 hit
//    ~21% -> ~62%+, cutting L3 gather traffic ~3x.
//    Per pass: 1 uint4 gather per neighbor, 8 accumulators, 4-way MLP.
// ---------------------------------------------------------------------------
__global__ __launch_bounds__(256) void spmm2_kernel(
    const float4* __restrict__ x4, const float4* __restrict__ scal,
    const int* __restrict__ adj_col, const int* __restrict__ row_ptr,
    const uint4* __restrict__ y1h, uint4* __restrict__ y2h, int n) {
    int t = threadIdx.x & 63;
    int f = t & 7;
    int r = (blockIdx.x * 4 + (threadIdx.x >> 6)) * 8 + (t >> 3);
    int g = blockIdx.y;
    if (r >= n) return;
    const uint4* yp = y1h + (size_t)g * PLANE_U4;

    int s = row_ptr[r], e = row_ptr[r + 1];
    int cnt = e - s;
    float a[8];
#pragma unroll
    for (int j = 0; j < 8; ++j) a[j] = 0.f;

    int i = 0;
    for (; i + 4 <= cnt; i += 4) {                 // 4 gathers in flight/octet
        int c0 = adj_col[s + i];
        int c1 = adj_col[s + i + 1];
        int c2 = adj_col[s + i + 2];
        int c3 = adj_col[s + i + 3];
        uint4 b0 = yp[(size_t)c0 * 8 + f];
        uint4 b1 = yp[(size_t)c1 * 8 + f];
        uint4 b2 = yp[(size_t)c2 * 8 + f];
        uint4 b3 = yp[(size_t)c3 * 8 + f];
        float f0[8], f1[8], f2[8], f3[8];
        unpack8(b0, f0); unpack8(b1, f1); unpack8(b2, f2); unpack8(b3, f3);
#pragma unroll
        for (int j = 0; j < 8; ++j)
            a[j] += (f0[j] + f1[j]) + (f2[j] + f3[j]);
    }
    for (; i < cnt; ++i) {
        int c = adj_col[s + i];
        uint4 b = yp[(size_t)c * 8 + f];
        float fv[8]; unpack8(b, fv);
#pragma unroll
        for (int j = 0; j < 8; ++j) a[j] += fv[j];
    }

    float4 sc = scal[r];                       // {1/d, rsqrt, sqrt, 0}
    float w = (g == 0) ? 1.0f : ((g == 1) ? sc.y : sc.z);
    float4 xa = x4[(size_t)r * 16 + f * 2];
    float4 xb = x4[(size_t)r * 16 + f * 2 + 1];
    float xr[8] = {xa.x, xa.y, xa.z, xa.w, xb.x, xb.y, xb.z, xb.w};
    float v[8];
#pragma unroll
    for (int j = 0; j < 8; ++j) v[j] = sc.x * a[j] - xr[j] * w;

    uint4* yr = y2h + (size_t)g * PLANE_U4 + (size_t)r * 8 + f;
    yr[0] = make_uint4(rne2(v[0], v[1]), rne2(v[2], v[3]),
                       rne2(v[4], v[5]), rne2(v[6], v[7]));
}

// ---------------------------------------------------------------------------
// 4) Output gather + [64,9] transpose through LDS; float4 store path.
//    out[ent, d, g]: g 0..2 = x*{1,rsqrt,sqrt}, g 3..5 = y1, g 6..8 = y2.
//    y1/y2 now plane-major: plane stride N*64 ushorts.
// ---------------------------------------------------------------------------
__global__ __launch_bounds__(256) void gather_kernel(
    const float* __restrict__ x, const float4* __restrict__ scal,
    const int* __restrict__ edge, const ushort16* __restrict__ y1h,
    const ushort16* __restrict__ y2h, float* __restrict__ out) {
    __shared__ __align__(16) float lds[4][576];
    int wave = threadIdx.x >> 6;
    int t    = threadIdx.x & 63;
    int ent  = blockIdx.x * 4 + wave;

    int n = edge[ent];
    float4 sc = scal[n];                       // {1/d, rsqrt, sqrt, 0}
    float xv = x[n * D_FEAT + t];
    size_t nb = (size_t)n * 64 + t;

    float h[9];
    h[0] = xv;                      h[1] = xv * sc.y;                h[2] = xv * sc.z;
    h[3] = bf1(y1h[nb]);            h[4] = bf1(y1h[nb + PLANE_US]);  h[5] = bf1(y1h[nb + 2*PLANE_US]);
    h[6] = bf1(y2h[nb]);            h[7] = bf1(y2h[nb + PLANE_US]);  h[8] = bf1(y2h[nb + 2*PLANE_US]);

#pragma unroll
    for (int g = 0; g < 9; ++g) lds[wave][t * 9 + g] = h[g];  // 2-way alias: free
    __syncthreads();

    const float4* l4 = (const float4*)lds[wave];
    float4* o4 = (float4*)(out + (size_t)ent * 576);   // 144 float4 per entry
    o4[t]      = l4[t];
    o4[t + 64] = l4[t + 64];
    if (t < 16) o4[t + 128] = l4[t + 128];
}

// ---------------------------------------------------------------------------
extern "C" void kernel_launch(void* const* d_in, const int* in_sizes, int n_in,
                              void* d_out, int out_size, void* d_ws, size_t ws_size,
                              hipStream_t stream) {
    const float* x       = (const float*)d_in[0];   // [N, 64]
    const float* deg     = (const float*)d_in[1];   // [N, 1]
    const int*   adj_row = (const int*)d_in[2];     // [nnz] sorted
    const int*   adj_col = (const int*)d_in[3];     // [nnz]
    const int*   edge    = (const int*)d_in[4];     // [2, 32768]
    float* out = (float*)d_out;

    // Workspace (rewritten fully every call):
    //   row_ptr : (N+1) int        scal : N float4
    //   xh      : N*64 bf16        y1h  : [3][N][64] bf16   y2h : [3][N][64] bf16
    char* ws = (char*)d_ws;
    size_t off = 0;
    int*    row_ptr = (int*)ws;            off = ((size_t)(N_NODES + 1) * 4 + 255) & ~(size_t)255;
    float4* scal    = (float4*)(ws + off); off += (size_t)N_NODES * 16;
    uint32* xh      = (uint32*)(ws + off); off += (size_t)N_NODES * 64 * 2;
    off = (off + 255) & ~(size_t)255;
    uint4*  y1h     = (uint4*)(ws + off);  off += (size_t)N_NODES * 192 * 2;
    off = (off + 255) & ~(size_t)255;
    uint4*  y2h     = (uint4*)(ws + off);

    int nblk = (N_NODES + 31) / 32;

    build_rowptr_scal<<<(N_NODES + 1 + 255) / 256, 256, 0, stream>>>(
        adj_row, deg, row_ptr, scal, N_NNZ, N_NODES);
    pack_x<<<(N_NODES * 32 + 255) / 256, 256, 0, stream>>>(
        (const float2*)x, xh, N_NODES * 32);
    spmm1_kernel<<<nblk, 256, 0, stream>>>(
        (const uint4*)xh, scal, adj_col, row_ptr, y1h, N_NODES);
    spmm2_kernel<<<dim3(nblk, 3), 256, 0, stream>>>(
        (const float4*)x, scal, adj_col, row_ptr, y1h, y2h, N_NODES);
    gather_kernel<<<N_ENT / 4, 256, 0, stream>>>(
        x, scal, edge, (const ushort16*)y1h, (const ushort16*)y2h, out);
}